// Round 7
// baseline (178.138 us; speedup 1.0000x reference)
//
#include <hip/hip_runtime.h>
#include <hip/hip_bf16.h>

#define N 4096
#define D 256
#define MARGIN 0.3f
#define NPANEL 64                       // 4096 / 64
#define NSLOT 65                        // partial slots per panel, each written once
#define NTILE (NPANEL * (NPANEL + 1) / 2)   // 2080 triangular tiles
#define NBLK 512                        // co-resident persistent grid (<= 4/CU * 256)
#define FLT_BIG 3.402823466e+38f

typedef __attribute__((ext_vector_type(8))) short short8;
typedef __attribute__((ext_vector_type(4))) float f32x4;
typedef const __attribute__((address_space(1))) unsigned char g1_t;
typedef __attribute__((address_space(3))) unsigned char l3_t;

__device__ __forceinline__ ushort f2bf(float f) {
    unsigned u = __float_as_uint(f);
    unsigned r = (u + 0x7fffu + ((u >> 16) & 1u)) >> 16;   // RNE
    return (ushort)r;
}

// Grid barrier: all NBLK blocks are co-resident (launch_bounds contract).
// Device-scope RMWs only — plain loads are not cross-XCD coherent.
__device__ __forceinline__ void grid_bar(unsigned* cnt, unsigned target) {
    __syncthreads();
    if (threadIdx.x == 0) {
        __threadfence();                          // release
        atomicAdd(cnt, 1u);
        while (atomicAdd(cnt, 0u) < target) __builtin_amdgcn_s_sleep(2);
    }
    __syncthreads();
    __threadfence();                              // acquire (all threads)
}

__global__ __launch_bounds__(256, 4) void fused_kernel(
        const float* __restrict__ feat, const int* __restrict__ labels,
        float* __restrict__ xx, ushort* __restrict__ hi,
        float* __restrict__ pPart, float* __restrict__ nPart,
        float* __restrict__ gacc, unsigned* __restrict__ ticket,
        unsigned* __restrict__ bar, float* __restrict__ out) {
    __shared__ __attribute__((aligned(16))) short sA[64 * 64];   // 8 KB
    __shared__ __attribute__((aligned(16))) short sB[64 * 64];   // 8 KB
    __shared__ float rp[4][32], rn[4][32], cp[4][32], cn[4][32]; // 2 KB
    __shared__ float ssum[4], scnt[4];

    const int tid  = threadIdx.x;
    const int lane = tid & 63;
    const int wid  = tid >> 6;
    const int bid  = blockIdx.x;

    // ---------- phase 0: bf16 convert + row squared norms (8 rows/block) ----
    {
        int rbase = bid * 8 + wid * 2;
        #pragma unroll
        for (int rr = 0; rr < 2; ++rr) {
            int row = rbase + rr;
            float4 v = *(const float4*)(feat + (size_t)row * D + lane * 4);
            *(ushort4*)(hi + (size_t)row * D + lane * 4) =
                make_ushort4(f2bf(v.x), f2bf(v.y), f2bf(v.z), f2bf(v.w));
            float s = v.x * v.x + v.y * v.y + v.z * v.z + v.w * v.w;
            #pragma unroll
            for (int off = 32; off >= 1; off >>= 1) s += __shfl_xor(s, off);
            if (lane == 0) xx[row] = s;
        }
    }
    grid_bar(bar, NBLK);

    // ---------- phase 1: triangular 64x64 bf16-MFMA tiles ---------------
    const int wr  = (wid >> 1) * 32;
    const int wc  = (wid & 1) * 32;
    const int l15 = lane & 15;
    const int kq  = (lane >> 4) * 8;
    const int swz = (lane & 7) << 3;       // ushort-index XOR swizzle (16B units)

    for (int tile = bid; tile < NTILE; tile += NBLK) {
        int t = tile, bi = 0, rem = NPANEL;
        while (t >= rem) { t -= rem; ++bi; --rem; }
        const int bj = bi + t;
        const int rowBase = bi * 64;
        const int colBase = bj * 64;

        f32x4 acc[2][2] = {};

        for (int kt = 0; kt < D; kt += 64) {
            #pragma unroll
            for (int i = 0; i < 2; ++i) {
                int c   = i * 256 + tid;          // 16B chunk index, 0..511
                int row = c >> 3;                 // 0..63
                int kc  = ((c ^ row) & 7) * 8;    // pre-swizzled global k-chunk
                __builtin_amdgcn_global_load_lds(
                    (g1_t*)(hi + (size_t)(rowBase + row) * D + kt + kc),
                    (l3_t*)(sA + c * 8), 16, 0, 0);
                __builtin_amdgcn_global_load_lds(
                    (g1_t*)(hi + (size_t)(colBase + row) * D + kt + kc),
                    (l3_t*)(sB + c * 8), 16, 0, 0);
            }
            __syncthreads();
            #pragma unroll
            for (int h = 0; h < 2; ++h) {
                short8 af[2], bfv[2];
                #pragma unroll
                for (int m = 0; m < 2; ++m) {
                    int idx = ((wr + m * 16 + l15) << 6) + h * 32 + kq;
                    af[m] = *(const short8*)(sA + (idx ^ swz));
                }
                #pragma unroll
                for (int n = 0; n < 2; ++n) {
                    int idx = ((wc + n * 16 + l15) << 6) + h * 32 + kq;
                    bfv[n] = *(const short8*)(sB + (idx ^ swz));
                }
                #pragma unroll
                for (int m = 0; m < 2; ++m)
                    #pragma unroll
                    for (int n = 0; n < 2; ++n)
                        acc[m][n] = __builtin_amdgcn_mfma_f32_16x16x32_bf16(
                            af[m], bfv[n], acc[m][n], 0, 0, 0);
            }
            __syncthreads();
        }

        // epilogue in d^2 domain
        float xr[2][4]; int lrow[2][4];
        #pragma unroll
        for (int m = 0; m < 2; ++m)
            #pragma unroll
            for (int j = 0; j < 4; ++j) {
                int rg = rowBase + wr + m * 16 + (lane >> 4) * 4 + j;
                xr[m][j] = xx[rg]; lrow[m][j] = labels[rg];
            }
        float xc[2]; int lcol[2];
        #pragma unroll
        for (int n = 0; n < 2; ++n) {
            int cg = colBase + wc + n * 16 + l15;
            xc[n] = xx[cg]; lcol[n] = labels[cg];
        }

        float pm2[2][4], nm2[2][4], cpm[2], cnm[2];
        #pragma unroll
        for (int m = 0; m < 2; ++m)
            #pragma unroll
            for (int j = 0; j < 4; ++j) { pm2[m][j] = 0.0f; nm2[m][j] = FLT_BIG; }
        #pragma unroll
        for (int n = 0; n < 2; ++n) { cpm[n] = 0.0f; cnm[n] = FLT_BIG; }

        #pragma unroll
        for (int m = 0; m < 2; ++m)
            #pragma unroll
            for (int n = 0; n < 2; ++n)
                #pragma unroll
                for (int j = 0; j < 4; ++j) {
                    float d2 = fmaxf(xr[m][j] + xc[n] - 2.0f * acc[m][n][j], 0.0f);
                    bool pos = (lrow[m][j] == lcol[n]);
                    if (pos) {
                        pm2[m][j] = fmaxf(pm2[m][j], d2);
                        cpm[n]    = fmaxf(cpm[n],    d2);
                    } else {
                        nm2[m][j] = fminf(nm2[m][j], d2);
                        cnm[n]    = fminf(cnm[n],    d2);
                    }
                }

        #pragma unroll
        for (int m = 0; m < 2; ++m)
            #pragma unroll
            for (int j = 0; j < 4; ++j) {
                #pragma unroll
                for (int off = 1; off <= 8; off <<= 1) {
                    pm2[m][j] = fmaxf(pm2[m][j], __shfl_xor(pm2[m][j], off));
                    nm2[m][j] = fminf(nm2[m][j], __shfl_xor(nm2[m][j], off));
                }
            }
        #pragma unroll
        for (int n = 0; n < 2; ++n) {
            #pragma unroll
            for (int off = 16; off <= 32; off <<= 1) {
                cpm[n] = fmaxf(cpm[n], __shfl_xor(cpm[n], off));
                cnm[n] = fminf(cnm[n], __shfl_xor(cnm[n], off));
            }
        }

        if (l15 == 0) {
            #pragma unroll
            for (int m = 0; m < 2; ++m)
                #pragma unroll
                for (int j = 0; j < 4; ++j) {
                    int r = m * 16 + (lane >> 4) * 4 + j;   // 0..31
                    rp[wid][r] = pm2[m][j]; rn[wid][r] = nm2[m][j];
                }
        }
        if (lane < 16) {
            #pragma unroll
            for (int n = 0; n < 2; ++n) {
                int c = n * 16 + l15;                        // 0..31
                cp[wid][c] = cpm[n]; cn[wid][c] = cnm[n];
            }
        }
        __syncthreads();

        // partial stores: rows -> slot bj+1, cols -> slot bi (each written once/panel)
        if (tid < 64) {
            int r = tid, pair = (r >> 5) * 2, rrr = r & 31;
            pPart[(size_t)(bj + 1) * N + rowBase + r] = fmaxf(rp[pair][rrr], rp[pair + 1][rrr]);
            nPart[(size_t)(bj + 1) * N + rowBase + r] = fminf(rn[pair][rrr], rn[pair + 1][rrr]);
        } else if (tid < 128) {
            int c = tid - 64, pair = c >> 5, cc = c & 31;
            pPart[(size_t)bi * N + colBase + c] = fmaxf(cp[pair][cc], cp[pair + 2][cc]);
            nPart[(size_t)bi * N + colBase + c] = fminf(cn[pair][cc], cn[pair + 2][cc]);
        }
        __syncthreads();
    }

    grid_bar(bar, 2 * NBLK);

    // ---------- phase 2: merge partials + loss (blocks 0..15), ticket finalize ---
    if (bid < 16) {
        int i = bid * 256 + tid;
        float ap2 = 0.0f, an2 = FLT_BIG;
        #pragma unroll 5
        for (int s = 0; s < NSLOT; ++s) {
            ap2 = fmaxf(ap2, pPart[(size_t)s * N + i]);
            an2 = fminf(an2, nPart[(size_t)s * N + i]);
        }
        float ap = sqrtf(fmaxf(ap2, 1e-12f));
        float an = sqrtf(fmaxf(an2, 1e-12f));
        bool valid = (ap < 1.0e6f) && (an > 0.0f);
        float per = valid ? fmaxf(MARGIN + ap - an, 0.0f) : 0.0f;
        float cnt = valid ? 1.0f : 0.0f;
        #pragma unroll
        for (int off = 32; off >= 1; off >>= 1) {
            per += __shfl_xor(per, off);
            cnt += __shfl_xor(cnt, off);
        }
        if (lane == 0) { ssum[wid] = per; scnt[wid] = cnt; }
        __syncthreads();
        if (tid == 0) {
            atomicAdd(&gacc[0], ssum[0] + ssum[1] + ssum[2] + ssum[3]);
            atomicAdd(&gacc[1], scnt[0] + scnt[1] + scnt[2] + scnt[3]);
        }
    }
    if (tid == 0) {
        __threadfence();
        unsigned tk = atomicAdd(ticket, 1u);
        if (tk == NBLK - 1) {            // last block: all adds visible
            float St = atomicAdd(&gacc[0], 0.0f);
            float Ct = atomicAdd(&gacc[1], 0.0f);
            out[0] = (Ct > 0.0f) ? St / fmaxf(Ct, 1.0f) : 0.0f;
        }
    }
}

extern "C" void kernel_launch(void* const* d_in, const int* in_sizes, int n_in,
                              void* d_out, int out_size, void* d_ws, size_t ws_size,
                              hipStream_t stream) {
    const float* feat = (const float*)d_in[0];
    const int* labels = (const int*)d_in[1];
    char* ws = (char*)d_ws;
    float*    xx     = (float*)ws;                                   // 16 KB
    float*    gacc   = (float*)(ws + 16384);                         // 8 B
    unsigned* ticket = (unsigned*)(ws + 16384 + 8);                  // 4 B
    unsigned* bar    = (unsigned*)(ws + 16384 + 12);                 // 4 B
    ushort*   hi     = (ushort*)(ws + 32768);                        // 2 MB
    float*    pPart  = (float*)(ws + 32768 + (size_t)N * D * 2);     // 1.04 MB
    float*    nPart  = (float*)(ws + 32768 + (size_t)N * D * 2
                                + (size_t)NSLOT * N * 4);            // 1.04 MB
    float* out = (float*)d_out;

    hipMemsetAsync(ws + 16384, 0, 64, stream);   // zero gacc/ticket/bar each call
    fused_kernel<<<NBLK, 256, 0, stream>>>(feat, labels, xx, hi,
                                           pPart, nPart, gacc, ticket, bar, out);
}